// Round 11
// baseline (160.661 us; speedup 1.0000x reference)
//
#include <hip/hip_runtime.h>
#include <math.h>

#define VOCAB 50000
#define EMBED 128
#define SEQ   200
#define HID   30
#define BATCH 4096

// HISTORY: r3/r6/r8 numeric failures were the float4-cast TBAA stale-read
// bug (fixed r9/r10 via memcpy/sched_barrier, absmax 0.0). Passing kernels
// hit absmax 0.0 vs numpy despite __expf!=libm tanh -> the recurrence DAMPS
// ulp perturbations; reassociation is acceptable. r10 counters: 4-rows/wave
// is latency-bound at 1 wave/SIMD (VALUBusy 27%). r11: h-transport moves to
// the VALU pipe (DPP rotate + one ds_swizzle), 2048 waves, LDS 10->2 ops/step.
__device__ __forceinline__ float tanh_fast(float x) {
    // tanh(x) = 1 - 2/(e^{2x}+1); IEEE divide (NOT __fdividef - accuracy).
    float e = __expf(2.0f * x);
    return 1.0f - 2.0f / (e + 1.0f);
}

__device__ __forceinline__ int ror1_i(int x) {      // row_ror:1 (16-lane rows)
    return __builtin_amdgcn_update_dpp(0, x, 0x121, 0xF, 0xF, false);
}
__device__ __forceinline__ float ror1_f(float x) {
    return __int_as_float(ror1_i(__float_as_int(x)));
}
__device__ __forceinline__ int swz16_i(int x) {     // lane ^= 16 (within 32)
    return __builtin_amdgcn_ds_swizzle(x, 0x401F);
}
__device__ __forceinline__ float swz16_f(float x) {
    return __int_as_float(swz16_i(__float_as_int(x)));
}

// Kernel 0: WxT[j][e] = Wx[e][j]  (15 KB; makes embproj's scalar loads
// consecutive so they merge into s_load_dwordx16)
__global__ __launch_bounds__(256) void wxT_kernel(
    const float* __restrict__ Wx, float* __restrict__ WxT)
{
    int idx = blockIdx.x * 256 + threadIdx.x;
    if (idx < EMBED * HID) {
        int j = idx >> 7;        // idx / 128
        int e = idx & 127;       // idx % 128
        WxT[idx] = Wx[e * HID + j];
    }
}

// Kernel 1: embP[v][j] = sum_e emb[v][e] * Wx[e][j] + b_rnn[j]
// Lane = one vocab row (er[] in 128 VGPRs). j is wave-uniform -> WxT/brnn
// go through the SMEM pipe; WxT rows are consecutive floats -> the 128
// unrolled loads merge into 8x s_load_dwordx16 per j (r5's version issued
// 3840 unmergeable stride-120B s_loads -- that was its 30us bottleneck).
// Per-(v,j) FP sequence identical to the proven r4/r7 order:
//   a_d += e[4q+d]*Wx[4q+d][j], q ascending, bias seeds a0, (a0+a1)+(a2+a3).
__global__ __launch_bounds__(256) void embproj_kernel(
    const float* __restrict__ emb, const float* __restrict__ WxT,
    const float* __restrict__ brnn, float* __restrict__ embP)
{
    int v  = blockIdx.x * 256 + threadIdx.x;
    int vc = min(v, VOCAB - 1);
    const float4* e4 = (const float4*)(emb + (size_t)vc * EMBED);

    float4 er[32];
    #pragma unroll
    for (int q = 0; q < 32; ++q) er[q] = e4[q];

    #pragma unroll 2
    for (int j = 0; j < HID; ++j) {
        const float* wj = WxT + j * EMBED;   // uniform -> scalar loads
        float a0 = brnn[j], a1 = 0.f, a2 = 0.f, a3 = 0.f;
        #pragma unroll
        for (int q = 0; q < 32; ++q) {
            a0 += er[q].x * wj[4 * q + 0];
            a1 += er[q].y * wj[4 * q + 1];
            a2 += er[q].z * wj[4 * q + 2];
            a3 += er[q].w * wj[4 * q + 3];
        }
        if (v < VOCAB)
            embP[(size_t)v * HID + j] = (a0 + a1) + (a2 + a3);
    }
}

// Kernel 2: fused RNN recurrence + dense head.
// Wave = 2 batch rows x 32 lanes (2048 waves = 2/SIMD). Lane j of a row
// OWNS h[j] in a register. Per step, the 30-value broadcast is:
//   rB = ds_swizzle_xor16(h)           (1 LDS-crossbar op)
//   15x v_mov_dpp row_ror:1 on each half (pure VALU)
// so LDS ops/step drop 10 -> 2 (swizzle + token read); no h store/load, no
// TBAA hazard, no fences. The Wh operand order per lane follows the rotation
// arrival order -- derived by applying the ACTUAL hw ops to the lane index
// (probe), so it is correct regardless of DPP direction semantics.
// k-summation order differs per lane (reassociation -- accepted, see header).
__global__ __launch_bounds__(256, 2) void rnn_head_kernel(
    const int* __restrict__ tokens, const float* __restrict__ embP,
    const float* __restrict__ Wh,
    const float* __restrict__ W1, const float* __restrict__ b1,
    const float* __restrict__ W2, const float* __restrict__ b2,
    const float* __restrict__ W3, const float* __restrict__ b3,
    const float* __restrict__ Wo, const float* __restrict__ bo,
    float* __restrict__ out)
{
    __shared__ int   tokL[8][SEQ];
    __shared__ float hL[8][32];
    __shared__ float d1L[8][128];
    __shared__ float d2L[8][64];

    int tid  = threadIdx.x;
    int wv   = tid >> 6;           // wave 0..3
    int l    = tid & 63;
    int half = l >> 5;             // row within wave
    int j    = l & 31;             // owned h index / output column
    int rloc = wv * 2 + half;      // row within block, 0..7
    int b    = blockIdx.x * 8 + rloc;

    // stage this row's tokens (wave-private; int-typed both sides)
    for (int i = j; i < SEQ; i += 32)
        tokL[rloc][i] = tokens[(size_t)b * SEQ + i];

    bool colv = (j < HID);

    // ---- arrival-order probe: run the exact transport ops on the lane
    // index so wA/wB match whatever the hardware permutation does ----
    float wA[16], wB[16];
    {
        int kA = j;                 // own value's k
        int kB = swz16_i(j);        // cross-half value's k
        #pragma unroll
        for (int N = 0; N < 16; ++N) {
            wA[N] = (colv && kA < HID) ? Wh[kA * HID + j] : 0.0f;
            wB[N] = (colv && kB < HID) ? Wh[kB * HID + j] : 0.0f;
            if (N < 15) { kA = ror1_i(kA); kB = ror1_i(kB); }
        }
    }

    // prefetch ring: xq[s] holds xp for step t+s (8 loads in flight)
    float xq[8];
    #pragma unroll
    for (int s = 0; s < 8; ++s) {
        int tk = tokL[rloc][s];
        xq[s] = colv ? embP[(size_t)tk * HID + j] : 0.0f;
    }

    float hreg = 0.0f;   // h0 = 0; lanes 30,31 stay 0 forever (gated below)

    for (int t = 0; t < SEQ; t += 8) {
        #pragma unroll
        for (int s = 0; s < 8; ++s) {
            int tf = t + 8 + s; tf = (tf < SEQ) ? tf : SEQ - 1;
            int tkn = tokL[rloc][tf];

            float a0 = xq[s], a1 = 0.0f;
            xq[s] = colv ? embP[(size_t)tkn * HID + j] : 0.0f;

            float rA = hreg;
            float rB = swz16_f(hreg);
            #pragma unroll
            for (int N = 0; N < 16; ++N) {
                a0 += rA * wA[N];
                a1 += rB * wB[N];
                if (N < 15) { rA = ror1_f(rA); rB = ror1_f(rB); }
            }
            float hn = tanh_fast(a0 + a1);
            hreg = colv ? hn : 0.0f;
        }
    }

    // stage final h for the head (float-typed both sides, wave-private)
    hL[rloc][j] = hreg;

    // ---- dense head: proven r7 code, each 32-lane half does its row ----
    {
        #pragma unroll
        for (int qq = 0; qq < 4; ++qq) {
            int c = j + 32 * qq;
            float acc = b1[c];
            #pragma unroll
            for (int k = 0; k < HID; ++k) acc += hL[rloc][k] * W1[k * 128 + c];
            d1L[rloc][c] = fmaxf(acc, 0.0f);
        }
        #pragma unroll
        for (int qq = 0; qq < 2; ++qq) {
            int c = j + 32 * qq;
            float acc = b2[c];
            #pragma unroll 8
            for (int k = 0; k < 128; ++k) acc += d1L[rloc][k] * W2[k * 64 + c];
            d2L[rloc][c] = fmaxf(acc, 0.0f);
        }
        float acc3 = b3[j];
        #pragma unroll 8
        for (int k = 0; k < 64; ++k) acc3 += d2L[rloc][k] * W3[k * 32 + j];
        acc3 = fmaxf(acc3, 0.0f);
        float prod = acc3 * Wo[j];
        #pragma unroll
        for (int m = 16; m > 0; m >>= 1) prod += __shfl_xor(prod, m, 32);
        if (j == 0) out[b] = 1.0f / (1.0f + __expf(-(prod + bo[0])));
    }
}

extern "C" void kernel_launch(void* const* d_in, const int* in_sizes, int n_in,
                              void* d_out, int out_size, void* d_ws, size_t ws_size,
                              hipStream_t stream) {
    (void)in_sizes; (void)n_in; (void)out_size; (void)ws_size;
    const int*   tokens = (const int*)  d_in[0];
    const float* emb    = (const float*)d_in[1];
    const float* Wx     = (const float*)d_in[2];
    const float* Wh     = (const float*)d_in[3];
    const float* brnn   = (const float*)d_in[4];
    const float* W1     = (const float*)d_in[5];
    const float* b1     = (const float*)d_in[6];
    const float* W2     = (const float*)d_in[7];
    const float* b2     = (const float*)d_in[8];
    const float* W3     = (const float*)d_in[9];
    const float* b3     = (const float*)d_in[10];
    const float* Wo     = (const float*)d_in[11];
    const float* bo     = (const float*)d_in[12];
    float* out  = (float*)d_out;
    float* embP = (float*)d_ws;                         // 6,000,000 B
    float* WxT  = (float*)((char*)d_ws + 6000000);      // + 15,360 B

    wxT_kernel<<<(EMBED * HID + 255) / 256, 256, 0, stream>>>(Wx, WxT);
    embproj_kernel<<<(VOCAB + 255) / 256, 256, 0, stream>>>(emb, WxT, brnn, embP);
    rnn_head_kernel<<<BATCH / 8, 256, 0, stream>>>(
        tokens, embP, Wh, W1, b1, W2, b2, W3, b3, Wo, bo, out);
}

// Round 12
// 128.516 us; speedup vs baseline: 1.2501x; 1.2501x over previous
//
#include <hip/hip_runtime.h>
#include <math.h>

#define VOCAB 50000
#define EMBED 128
#define SEQ   200
#define HID   30
#define BATCH 4096

// HISTORY: r3/r6/r8 failures = TBAA stale-h reads (float4 cast). r9/r10
// fixed ordering via __builtin_memcpy -> absmax 0.0, but memcpy likely
// lowered to 4x ds_read_b32 (+movs), quadrupling LDS-pipe traffic (measured
// ~1160 cyc/step vs 432 model). r11 DPP transport: serial VALU chain, worse.
// r12: same r10 structure, but hv loads via may_alias float4 typedef ->
// real ds_read_b128 with mandatory ordering vs the float h-stores.
typedef float4 __attribute__((__may_alias__)) f4ma;

__device__ __forceinline__ float tanh_fast(float x) {
    // tanh(x) = 1 - 2/(e^{2x}+1); IEEE divide (NOT __fdividef - accuracy).
    float e = __expf(2.0f * x);
    return 1.0f - 2.0f / (e + 1.0f);
}

// Kernel 1: embP[v][j] = sum_e emb[v][e] * Wx[e][j] + b_rnn[j]
// BYTE-IDENTICAL to the round-4/7 pass. Do not touch.
__global__ __launch_bounds__(256) void embproj_kernel(
    const float* __restrict__ emb, const float* __restrict__ Wx,
    const float* __restrict__ brnn, float* __restrict__ embP)
{
    __shared__ float WxL[EMBED * HID];
    __shared__ float bL[32];
    int tid = threadIdx.x;
    for (int i = tid; i < EMBED * HID; i += 256) WxL[i] = Wx[i];
    if (tid < HID) bL[tid] = brnn[tid];
    __syncthreads();

    int g  = tid >> 5;
    int j  = tid & 31;
    int jj = (j < HID) ? j : 0;        // clamp LDS column for pad lanes
    int v0 = blockIdx.x * 32 + g * 4;

    int vr0 = min(v0 + 0, VOCAB - 1);
    int vr1 = min(v0 + 1, VOCAB - 1);
    int vr2 = min(v0 + 2, VOCAB - 1);
    int vr3 = min(v0 + 3, VOCAB - 1);
    const float4* e0 = (const float4*)(emb + (size_t)vr0 * EMBED);
    const float4* e1 = (const float4*)(emb + (size_t)vr1 * EMBED);
    const float4* e2 = (const float4*)(emb + (size_t)vr2 * EMBED);
    const float4* e3 = (const float4*)(emb + (size_t)vr3 * EMBED);

    float bj = (j < HID) ? bL[jj] : 0.0f;
    float acc[4][4];
    #pragma unroll
    for (int rr = 0; rr < 4; ++rr) {
        acc[rr][0] = bj; acc[rr][1] = 0.f; acc[rr][2] = 0.f; acc[rr][3] = 0.f;
    }

    #pragma unroll 4
    for (int q = 0; q < EMBED / 4; ++q) {
        float4 r0 = e0[q], r1 = e1[q], r2 = e2[q], r3 = e3[q];
        #pragma unroll
        for (int d = 0; d < 4; ++d) {
            float w = WxL[(4 * q + d) * HID + jj];
            acc[0][d] += (&r0.x)[d] * w;
            acc[1][d] += (&r1.x)[d] * w;
            acc[2][d] += (&r2.x)[d] * w;
            acc[3][d] += (&r3.x)[d] * w;
        }
    }
    if (j < HID) {
        #pragma unroll
        for (int rr = 0; rr < 4; ++rr) {
            if (v0 + rr < VOCAB)
                embP[(size_t)(v0 + rr) * HID + j] =
                    (acc[rr][0] + acc[rr][1]) + (acc[rr][2] + acc[rr][3]);
        }
    }
}

// Kernel 2: fused RNN recurrence + dense head.
// Structure byte-identical to r10 (passed, absmax 0.0) EXCEPT the hL access
// instructions: reads via may_alias float4 (real ds_read_b128, ordered vs
// the float stores by aliasing rules), writes as plain float stores.
// Wave = 4 batch rows x 16 lanes; lane computes cols jj and jj+16.
// LDS model: 4 waves/CU x (8 b128 + write + tok) ~= 432 cyc/CU-step.
__global__ __launch_bounds__(128, 1) void rnn_head_kernel(
    const int* __restrict__ tokens, const float* __restrict__ embP,
    const float* __restrict__ Wh,
    const float* __restrict__ W1, const float* __restrict__ b1,
    const float* __restrict__ W2, const float* __restrict__ b2,
    const float* __restrict__ W3, const float* __restrict__ b3,
    const float* __restrict__ Wo, const float* __restrict__ bo,
    float* __restrict__ out)
{
    __shared__ int tokL[8][SEQ];
    __shared__ __align__(16) float hL[8][48];   // stride 48: 2-way banks (free)
    __shared__ float d1L[8][128];
    __shared__ float d2L[8][64];

    int tid  = threadIdx.x;
    int wv   = tid >> 6;            // wave 0..1
    int l    = tid & 63;
    int q4   = l >> 4;              // row-in-wave 0..3
    int jj   = l & 15;              // column A; column B = jj+16
    int rloc = wv * 4 + q4;         // row within block, 0..7
    int jB   = jj + 16;
    int b    = blockIdx.x * 8 + rloc;

    // stage this row's tokens (wave-private -> in-wave DS order, no barrier)
    for (int i = jj; i < SEQ; i += 16)
        tokL[rloc][i] = tokens[(size_t)b * SEQ + i];

    hL[rloc][jj] = 0.0f;            // h0 = 0
    hL[rloc][jB] = 0.0f;            // cols 30,31 zeroed here, never rewritten
    __builtin_amdgcn_sched_barrier(0);   // init stores precede first reads

    float whcA[HID], whcB[HID];
    #pragma unroll
    for (int k = 0; k < HID; ++k) {
        whcA[k] = Wh[k * HID + jj];                      // jj < 16 < 30
        whcB[k] = (jB < HID) ? Wh[k * HID + jB] : 0.0f;  // cols 30,31 -> 0
    }

    bool ldB = (jB < HID);
    // prefetch ring: 8 steps ahead, 2 gathers/lane/step (16 loads in flight)
    float xqA[8], xqB[8];
    #pragma unroll
    for (int s = 0; s < 8; ++s) {
        int tk = tokL[rloc][s];
        xqA[s] = embP[(size_t)tk * HID + jj];
        xqB[s] = ldB ? embP[(size_t)tk * HID + jB] : 0.0f;
    }

    for (int t = 0; t < SEQ; t += 8) {
        #pragma unroll
        for (int s = 0; s < 8; ++s) {
            // consume ring slot, then refill it immediately
            float a0 = xqA[s], a1 = 0.0f;
            float c0 = xqB[s], c1 = 0.0f;
            int tf = t + 8 + s; tf = (tf < SEQ) ? tf : SEQ - 1;
            int tkn = tokL[rloc][tf];
            xqA[s] = embP[(size_t)tkn * HID + jj];
            xqB[s] = ldB ? embP[(size_t)tkn * HID + jB] : 0.0f;

            // 8x REAL ds_read_b128 (may_alias -> ordered vs float stores);
            // each read serves all 4 rows of the wave
            float hv[32];
            const f4ma* h4 = (const f4ma*)(&hL[rloc][0]);
            #pragma unroll
            for (int qq = 0; qq < 8; ++qq) {
                f4ma hh = h4[qq];
                hv[4*qq+0] = hh.x; hv[4*qq+1] = hh.y;
                hv[4*qq+2] = hh.z; hv[4*qq+3] = hh.w;
            }
            // two columns, each the exact proven even/odd chain
            #pragma unroll
            for (int k = 0; k < HID; k += 2) {
                a0 += hv[k]     * whcA[k];
                a1 += hv[k + 1] * whcA[k + 1];
                c0 += hv[k]     * whcB[k];
                c1 += hv[k + 1] * whcB[k + 1];
            }
            float hnA = tanh_fast(a0 + a1);
            float hnB = tanh_fast(c0 + c1);   // cols 30,31: tanh(0), write gated
            hL[rloc][jj] = hnA;
            if (ldB) hL[rloc][jB] = hnB;
            // pin store -> next-step-read order; NO waitcnt side effects
            __builtin_amdgcn_sched_barrier(0);
        }
    }

    // ---- dense head: proven code per 32-lane half; 2 passes = 4 rows/wave ----
    int half = l >> 5, l32 = l & 31;
    #pragma unroll
    for (int pp = 0; pp < 2; ++pp) {
        int rh = wv * 4 + half * 2 + pp;     // this wave's rows only
        int bB = blockIdx.x * 8 + rh;
        float hs[HID];
        #pragma unroll
        for (int k = 0; k < HID; ++k) hs[k] = hL[rh][k];

        #pragma unroll
        for (int qq = 0; qq < 4; ++qq) {
            int c = l32 + 32 * qq;
            float acc = b1[c];
            #pragma unroll
            for (int k = 0; k < HID; ++k) acc += hs[k] * W1[k * 128 + c];
            d1L[rh][c] = fmaxf(acc, 0.0f);
        }
        #pragma unroll
        for (int qq = 0; qq < 2; ++qq) {
            int c = l32 + 32 * qq;
            float acc = b2[c];
            #pragma unroll 8
            for (int k = 0; k < 128; ++k) acc += d1L[rh][k] * W2[k * 64 + c];
            d2L[rh][c] = fmaxf(acc, 0.0f);
        }
        float acc3 = b3[l32];
        #pragma unroll 8
        for (int k = 0; k < 64; ++k) acc3 += d2L[rh][k] * W3[k * 32 + l32];
        acc3 = fmaxf(acc3, 0.0f);
        float prod = acc3 * Wo[l32];
        #pragma unroll
        for (int m = 16; m > 0; m >>= 1) prod += __shfl_xor(prod, m, 32);
        if (l32 == 0) out[bB] = 1.0f / (1.0f + __expf(-(prod + bo[0])));
    }
}

extern "C" void kernel_launch(void* const* d_in, const int* in_sizes, int n_in,
                              void* d_out, int out_size, void* d_ws, size_t ws_size,
                              hipStream_t stream) {
    (void)in_sizes; (void)n_in; (void)out_size; (void)ws_size;
    const int*   tokens = (const int*)  d_in[0];
    const float* emb    = (const float*)d_in[1];
    const float* Wx     = (const float*)d_in[2];
    const float* Wh     = (const float*)d_in[3];
    const float* brnn   = (const float*)d_in[4];
    const float* W1     = (const float*)d_in[5];
    const float* b1     = (const float*)d_in[6];
    const float* W2     = (const float*)d_in[7];
    const float* b2     = (const float*)d_in[8];
    const float* W3     = (const float*)d_in[9];
    const float* b3     = (const float*)d_in[10];
    const float* Wo     = (const float*)d_in[11];
    const float* bo     = (const float*)d_in[12];
    float* out  = (float*)d_out;
    float* embP = (float*)d_ws;   // 50000*30*4 = 6 MB

    embproj_kernel<<<(VOCAB + 31) / 32, 256, 0, stream>>>(emb, Wx, brnn, embP);
    rnn_head_kernel<<<BATCH / 8, 128, 0, stream>>>(
        tokens, embP, Wh, W1, b1, W2, b2, W3, b3, Wo, bo, out);
}

// Round 15
// 106.981 us; speedup vs baseline: 1.5018x; 1.2013x over previous
//
#include <hip/hip_runtime.h>
#include <math.h>

#define VOCAB 50000
#define EMBED 128
#define SEQ   200
#define HID   30
#define BATCH 4096

// MODEL (r4/r7/r12 evidence): wall-clock = 200 x per-wave serial step
// latency (~1060 cyc at r7); occupancy/LDS-throughput are NOT binding.
// r13 cuts the serial chain: __fdividef tanh (no IEEE div expansion),
// 4-acc FMA chains, global token ring (lgkm queue = hv reads only),
// unconditional clamped loads (no exec-mask dance).
// NUMERIC SAFETY: r3/r6/r8 failures were the float4-TBAA stale-read bug
// (proven r9-r12); r11 passed absmax 0.0 under total reassociation -> the
// contractive recurrence damps ulp perturbations; ~2ulp __fdividef is safe.
typedef float4 __attribute__((__may_alias__)) f4ma;

__device__ __forceinline__ float tanh_fast(float x) {
    // tanh(x) = 1 - 2/(e^{2x}+1); v_rcp-based divide (~2ulp, damped).
    float e = __expf(2.0f * x);
    return 1.0f - __fdividef(2.0f, e + 1.0f);
}

// Kernel 1: embP[v][j] = sum_e emb[v][e] * Wx[e][j] + b_rnn[j]
// BYTE-IDENTICAL to the round-4/7 pass. Do not touch.
__global__ __launch_bounds__(256) void embproj_kernel(
    const float* __restrict__ emb, const float* __restrict__ Wx,
    const float* __restrict__ brnn, float* __restrict__ embP)
{
    __shared__ float WxL[EMBED * HID];
    __shared__ float bL[32];
    int tid = threadIdx.x;
    for (int i = tid; i < EMBED * HID; i += 256) WxL[i] = Wx[i];
    if (tid < HID) bL[tid] = brnn[tid];
    __syncthreads();

    int g  = tid >> 5;
    int j  = tid & 31;
    int jj = (j < HID) ? j : 0;        // clamp LDS column for pad lanes
    int v0 = blockIdx.x * 32 + g * 4;

    int vr0 = min(v0 + 0, VOCAB - 1);
    int vr1 = min(v0 + 1, VOCAB - 1);
    int vr2 = min(v0 + 2, VOCAB - 1);
    int vr3 = min(v0 + 3, VOCAB - 1);
    const float4* e0 = (const float4*)(emb + (size_t)vr0 * EMBED);
    const float4* e1 = (const float4*)(emb + (size_t)vr1 * EMBED);
    const float4* e2 = (const float4*)(emb + (size_t)vr2 * EMBED);
    const float4* e3 = (const float4*)(emb + (size_t)vr3 * EMBED);

    float bj = (j < HID) ? bL[jj] : 0.0f;
    float acc[4][4];
    #pragma unroll
    for (int rr = 0; rr < 4; ++rr) {
        acc[rr][0] = bj; acc[rr][1] = 0.f; acc[rr][2] = 0.f; acc[rr][3] = 0.f;
    }

    #pragma unroll 4
    for (int q = 0; q < EMBED / 4; ++q) {
        float4 r0 = e0[q], r1 = e1[q], r2 = e2[q], r3 = e3[q];
        #pragma unroll
        for (int d = 0; d < 4; ++d) {
            float w = WxL[(4 * q + d) * HID + jj];
            acc[0][d] += (&r0.x)[d] * w;
            acc[1][d] += (&r1.x)[d] * w;
            acc[2][d] += (&r2.x)[d] * w;
            acc[3][d] += (&r3.x)[d] * w;
        }
    }
    if (j < HID) {
        #pragma unroll
        for (int rr = 0; rr < 4; ++rr) {
            if (v0 + rr < VOCAB)
                embP[(size_t)(v0 + rr) * HID + j] =
                    (acc[rr][0] + acc[rr][1]) + (acc[rr][2] + acc[rr][3]);
        }
    }
}

// Kernel 2: fused RNN recurrence + dense head.
// r7 shape (wave = 2 rows x 32 lanes, 2048 waves) + serial-latency cuts.
// Per step (serial path): 8x ds_read_b128 (may_alias, ordered) -> 8x4 FMA
// (4 accs) -> __expf + v_rcp divide + fma -> gated h store -> sched_barrier.
// Off-path: embP ring refill (8-deep) + token ring refill (global, 8-deep,
// feeding the embP ring 8 steps later). No tokL, no predicated loads.
__global__ __launch_bounds__(256, 2) void rnn_head_kernel(
    const int* __restrict__ tokens, const float* __restrict__ embP,
    const float* __restrict__ Wh,
    const float* __restrict__ W1, const float* __restrict__ b1,
    const float* __restrict__ W2, const float* __restrict__ b2,
    const float* __restrict__ W3, const float* __restrict__ b3,
    const float* __restrict__ Wo, const float* __restrict__ bo,
    float* __restrict__ out)
{
    __shared__ __align__(16) float hL[8][36];   // 144B stride: aligned, 2-row bank-spread
    __shared__ float d1L[8][128];
    __shared__ float d2L[8][64];

    int tid  = threadIdx.x;
    int wv   = tid >> 6;           // wave 0..3
    int l    = tid & 63;
    int half = l >> 5;             // row within wave
    int j    = l & 31;             // column
    int rloc = wv * 2 + half;      // row within block, 0..7
    int b    = blockIdx.x * 8 + rloc;

    const int* trow = tokens + (size_t)b * SEQ;
    int jc = (j < HID) ? j : (HID - 1);   // clamped col: loads unconditional

    hL[rloc][j] = 0.0f;            // h0 = 0; pads 30,31 stay 0 forever
    __builtin_amdgcn_sched_barrier(0);

    float whc[32];
    #pragma unroll
    for (int k = 0; k < 32; ++k)
        whc[k] = (k < HID && j < HID) ? Wh[k * HID + j] : 0.0f;

    // two-level pipeline: xq[s] = xp for step t+s; tr[s] = token for t+8+s
    float xq[8];
    int   tr[8];
    #pragma unroll
    for (int s = 0; s < 8; ++s) {
        xq[s] = embP[(size_t)trow[s] * HID + jc];
        tr[s] = trow[8 + s];
    }

    for (int t = 0; t < SEQ; t += 8) {
        #pragma unroll
        for (int s = 0; s < 8; ++s) {
            // 8x ds_read_b128 FIRST (serial-critical: starts the LDS RT)
            float hv[32];
            const f4ma* h4 = (const f4ma*)(&hL[rloc][0]);
            #pragma unroll
            for (int qq = 0; qq < 8; ++qq) {
                f4ma hh = h4[qq];
                hv[4*qq+0] = hh.x; hv[4*qq+1] = hh.y;
                hv[4*qq+2] = hh.z; hv[4*qq+3] = hh.w;
            }
            // ring refills fill the read-latency window (8-step slack each)
            float a0 = xq[s], a1 = 0.0f, a2 = 0.0f, a3 = 0.0f;
            xq[s] = embP[(size_t)tr[s] * HID + jc];
            int tn = t + 16 + s; tn = (tn < SEQ) ? tn : SEQ - 1;
            tr[s] = trow[tn];

            // 4-acc FMA chains, depth 8 (whc/hv pads are exact zeros)
            #pragma unroll
            for (int k = 0; k < 32; k += 4) {
                a0 += hv[k]     * whc[k];
                a1 += hv[k + 1] * whc[k + 1];
                a2 += hv[k + 2] * whc[k + 2];
                a3 += hv[k + 3] * whc[k + 3];
            }
            float hn = tanh_fast((a0 + a1) + (a2 + a3));
            if (j < HID) hL[rloc][j] = hn;
            __builtin_amdgcn_sched_barrier(0);   // store precedes next reads
        }
    }

    // ---- dense head: r7 code verbatim, each 32-lane half does its row ----
    {
        #pragma unroll
        for (int qq = 0; qq < 4; ++qq) {
            int c = j + 32 * qq;
            float acc = b1[c];
            #pragma unroll
            for (int k = 0; k < HID; ++k) acc += hL[rloc][k] * W1[k * 128 + c];
            d1L[rloc][c] = fmaxf(acc, 0.0f);
        }
        #pragma unroll
        for (int qq = 0; qq < 2; ++qq) {
            int c = j + 32 * qq;
            float acc = b2[c];
            #pragma unroll 8
            for (int k = 0; k < 128; ++k) acc += d1L[rloc][k] * W2[k * 64 + c];
            d2L[rloc][c] = fmaxf(acc, 0.0f);
        }
        float acc3 = b3[j];
        #pragma unroll 8
        for (int k = 0; k < 64; ++k) acc3 += d2L[rloc][k] * W3[k * 32 + j];
        acc3 = fmaxf(acc3, 0.0f);
        float prod = acc3 * Wo[j];
        #pragma unroll
        for (int m = 16; m > 0; m >>= 1) prod += __shfl_xor(prod, m, 32);
        if (j == 0) out[b] = 1.0f / (1.0f + __expf(-(prod + bo[0])));
    }
}

extern "C" void kernel_launch(void* const* d_in, const int* in_sizes, int n_in,
                              void* d_out, int out_size, void* d_ws, size_t ws_size,
                              hipStream_t stream) {
    (void)in_sizes; (void)n_in; (void)out_size; (void)ws_size;
    const int*   tokens = (const int*)  d_in[0];
    const float* emb    = (const float*)d_in[1];
    const float* Wx     = (const float*)d_in[2];
    const float* Wh     = (const float*)d_in[3];
    const float* brnn   = (const float*)d_in[4];
    const float* W1     = (const float*)d_in[5];
    const float* b1     = (const float*)d_in[6];
    const float* W2     = (const float*)d_in[7];
    const float* b2     = (const float*)d_in[8];
    const float* W3     = (const float*)d_in[9];
    const float* b3     = (const float*)d_in[10];
    const float* Wo     = (const float*)d_in[11];
    const float* bo     = (const float*)d_in[12];
    float* out  = (float*)d_out;
    float* embP = (float*)d_ws;   // 50000*30*4 = 6 MB

    embproj_kernel<<<(VOCAB + 31) / 32, 256, 0, stream>>>(emb, Wx, brnn, embP);
    rnn_head_kernel<<<BATCH / 8, 256, 0, stream>>>(
        tokens, embP, Wh, W1, b1, W2, b2, W3, b3, Wo, bo, out);
}

// Round 16
// 95.563 us; speedup vs baseline: 1.6812x; 1.1195x over previous
//
#include <hip/hip_runtime.h>
#include <math.h>

#define VOCAB 50000
#define EMBED 128
#define SEQ   200
#define HID   30
#define BATCH 4096

// MODEL (r15 fit): rnn is LDS-INSTRUCTION-throughput bound: 8 waves/CU x
// (8 b128 + 2 misc) ~= 864 cyc/CU-step vs 977 measured. b128 costs ~12 cyc
// regardless of address count (no broadcast compression, m134/m136), so the
// fix is fewer/narrower LDS ops: split-K (4 b128/lane) + ONE ds_swizzle
// (send = p?pA:pB trick). Reassociation proven safe (r11 absmax 0.0 under
// total reorder); TBAA discipline (may_alias + sched_barrier) retained.
// embproj: rewritten LDS-free (Wx half-col in 64 VGPRs, rows partitioned
// across 2048 waves, double-buffered row loads) -- old design burned
// 128 ds_read_b32/thread + 32x-redundant VMEM (~25us for ~5us of work).
typedef float4 __attribute__((__may_alias__)) f4ma;

__device__ __forceinline__ float tanh_fast(float x) {
    // tanh(x) = 1 - 2/(e^{2x}+1); v_rcp divide (~2ulp, damped by recurrence)
    float e = __expf(2.0f * x);
    return 1.0f - __fdividef(2.0f, e + 1.0f);
}
__device__ __forceinline__ float swz16_f(float x) {   // lane ^= 16 (r11-proven)
    return __int_as_float(__builtin_amdgcn_ds_swizzle(__float_as_int(x), 0x401F));
}

// Kernel 1: embP[v][j] = sum_e emb[v][e] * Wx[e][j] + b_rnn[j]
// Wave = (j16, p, g): col = j16+16g (32 cols), k-half p (64 k each).
// Lane holds Wx[64p..64p+63][col] in 64 VGPRs (one-time strided loads).
// 2048 waves x ~25 rows each; per row: 16 same-addr-broadcast float4 loads
// (double-buffered across rows), 64 FMA, 1 swizzle combine, coalesced store.
__global__ __launch_bounds__(256, 2) void embproj_kernel(
    const float* __restrict__ emb, const float* __restrict__ Wx,
    const float* __restrict__ brnn, float* __restrict__ embP)
{
    int tid  = threadIdx.x;
    int wv   = tid >> 6;
    int l    = tid & 63;
    int j16  = l & 15;
    int p    = (l >> 4) & 1;
    int g    = l >> 5;
    int col  = j16 + 16 * g;                 // 0..31
    int colc = (col < HID) ? col : (HID - 1);
    int k0   = 64 * p;

    float whx[64];
    #pragma unroll
    for (int i = 0; i < 64; ++i)
        whx[i] = Wx[(k0 + i) * HID + colc];
    float bj = brnn[colc];

    int base = (blockIdx.x * 4 + wv) * 25;   // this wave's first row

    float4 eA[16], eB[16];
    #define LOADROW(dst, v) { \
        int vc = min((v), VOCAB - 1); \
        const f4ma* e4 = (const f4ma*)(emb + (size_t)vc * EMBED + k0); \
        _Pragma("unroll") \
        for (int q = 0; q < 16; ++q) dst[q] = e4[q]; \
    }
    #define COMPUTE(src, v) { \
        float a0 = 0.f, a1 = 0.f, a2 = 0.f, a3 = 0.f; \
        _Pragma("unroll") \
        for (int q = 0; q < 16; ++q) { \
            a0 += src[q].x * whx[4*q+0]; \
            a1 += src[q].y * whx[4*q+1]; \
            a2 += src[q].z * whx[4*q+2]; \
            a3 += src[q].w * whx[4*q+3]; \
        } \
        float own  = (a0 + a1) + (a2 + a3); \
        float full = bj + (own + swz16_f(own)); \
        if (p == 0 && col < HID && (v) < VOCAB) \
            embP[(size_t)(v) * HID + col] = full; \
    }

    LOADROW(eA, base + 0);
    for (int r = 0; r < 25; r += 2) {
        LOADROW(eB, base + r + 1);
        COMPUTE(eA, base + r);
        LOADROW(eA, base + r + 2);
        COMPUTE(eB, base + r + 1);
    }
    // row base+25 may be double-written (also next wave's row 0) with the
    // identical value -- benign.
    #undef LOADROW
    #undef COMPUTE
}

// Kernel 2: fused RNN recurrence + dense head.
// Wave = 2 rows x 32 lanes; within a row: lane (j16, p) computes BOTH
// cols {j16, j16+16} partials over k-half [16p,16p+16) -> reads 64 B
// (4 b128). ONE ds_swizzle(xor16): send = p?pA:pB delivers exactly the
// partner's missing half; own col full sum = own + recv. 1 tanh/lane.
// LDS/wave-step: 4 b128 + 1 swz + 1 store (was 8 b128 + 2).
// hL[8][32]: 128-B row stride -> all LDS ops <=2-way (free, m136).
__global__ __launch_bounds__(256, 2) void rnn_head_kernel(
    const int* __restrict__ tokens, const float* __restrict__ embP,
    const float* __restrict__ Wh,
    const float* __restrict__ W1, const float* __restrict__ b1,
    const float* __restrict__ W2, const float* __restrict__ b2,
    const float* __restrict__ W3, const float* __restrict__ b3,
    const float* __restrict__ Wo, const float* __restrict__ bo,
    float* __restrict__ out)
{
    __shared__ __align__(16) float hL[8][32];
    __shared__ float d1L[8][128];
    __shared__ float d2L[8][64];

    int tid  = threadIdx.x;
    int wv   = tid >> 6;           // wave 0..3
    int l    = tid & 63;
    int half = l >> 5;             // row within wave
    int j    = l & 31;             // own column
    int j16  = l & 15;
    int p    = (l >> 4) & 1;       // k-half
    int rloc = wv * 2 + half;      // row within block
    int b    = blockIdx.x * 8 + rloc;

    const int* trow = tokens + (size_t)b * SEQ;
    int jc = (j < HID) ? j : (HID - 1);

    hL[rloc][j] = 0.0f;            // h0 = 0; cols 30,31 stay 0 forever
    __builtin_amdgcn_sched_barrier(0);

    int cB = j16 + 16;
    float whA[16], whB[16];
    #pragma unroll
    for (int kk = 0; kk < 16; ++kk) {
        int k = 16 * p + kk;
        whA[kk] = (k < HID) ? Wh[k * HID + j16] : 0.0f;
        whB[kk] = (k < HID && cB < HID) ? Wh[k * HID + cB] : 0.0f;
    }

    // two-level pipeline: xq[s] = xp for step t+s; tr[s] = token for t+8+s
    float xq[8]; int tr[8];
    #pragma unroll
    for (int s = 0; s < 8; ++s) {
        xq[s] = embP[(size_t)trow[s] * HID + jc];
        tr[s] = trow[8 + s];
    }

    for (int t = 0; t < SEQ; t += 8) {
        #pragma unroll
        for (int s = 0; s < 8; ++s) {
            // 4x ds_read_b128: this lane's k-half of h
            float hv[16];
            const f4ma* h4 = (const f4ma*)(&hL[rloc][16 * p]);
            #pragma unroll
            for (int qq = 0; qq < 4; ++qq) {
                f4ma hh = h4[qq];
                hv[4*qq+0] = hh.x; hv[4*qq+1] = hh.y;
                hv[4*qq+2] = hh.z; hv[4*qq+3] = hh.w;
            }
            // ring refills in the read-latency window
            float xp = xq[s];
            xq[s] = embP[(size_t)tr[s] * HID + jc];
            int tn = t + 16 + s; tn = (tn < SEQ) ? tn : SEQ - 1;
            tr[s] = trow[tn];

            // both columns' partials over own k-half (4 chains, depth 8)
            float a0=0.f, a1=0.f, b0=0.f, b1=0.f;
            #pragma unroll
            for (int kk = 0; kk < 16; kk += 2) {
                a0 += hv[kk]   * whA[kk];
                a1 += hv[kk+1] * whA[kk+1];
                b0 += hv[kk]   * whB[kk];
                b1 += hv[kk+1] * whB[kk+1];
            }
            float pA = a0 + a1;           // col j16    , k-half p
            float pB = b0 + b1;           // col j16+16 , k-half p
            float own  = p ? pB : pA;     // own col's partial
            float send = p ? pA : pB;     // exactly what the partner needs
            float recv = swz16_f(send);
            float hn = tanh_fast(xp + (own + recv));
            if (j < HID) hL[rloc][j] = hn;
            __builtin_amdgcn_sched_barrier(0);   // store precedes next reads
        }
    }

    // ---- dense head: r7 code verbatim, each 32-lane half does its row ----
    {
        #pragma unroll
        for (int qq = 0; qq < 4; ++qq) {
            int c = j + 32 * qq;
            float acc = b1[c];
            #pragma unroll
            for (int k = 0; k < HID; ++k) acc += hL[rloc][k] * W1[k * 128 + c];
            d1L[rloc][c] = fmaxf(acc, 0.0f);
        }
        #pragma unroll
        for (int qq = 0; qq < 2; ++qq) {
            int c = j + 32 * qq;
            float acc = b2[c];
            #pragma unroll 8
            for (int k = 0; k < 128; ++k) acc += d1L[rloc][k] * W2[k * 64 + c];
            d2L[rloc][c] = fmaxf(acc, 0.0f);
        }
        float acc3 = b3[j];
        #pragma unroll 8
        for (int k = 0; k < 64; ++k) acc3 += d2L[rloc][k] * W3[k * 32 + j];
        acc3 = fmaxf(acc3, 0.0f);
        float prod = acc3 * Wo[j];
        #pragma unroll
        for (int m = 16; m > 0; m >>= 1) prod += __shfl_xor(prod, m, 32);
        if (j == 0) out[b] = 1.0f / (1.0f + __expf(-(prod + bo[0])));
    }
}

extern "C" void kernel_launch(void* const* d_in, const int* in_sizes, int n_in,
                              void* d_out, int out_size, void* d_ws, size_t ws_size,
                              hipStream_t stream) {
    (void)in_sizes; (void)n_in; (void)out_size; (void)ws_size;
    const int*   tokens = (const int*)  d_in[0];
    const float* emb    = (const float*)d_in[1];
    const float* Wx     = (const float*)d_in[2];
    const float* Wh     = (const float*)d_in[3];
    const float* brnn   = (const float*)d_in[4];
    const float* W1     = (const float*)d_in[5];
    const float* b1     = (const float*)d_in[6];
    const float* W2     = (const float*)d_in[7];
    const float* b2     = (const float*)d_in[8];
    const float* W3     = (const float*)d_in[9];
    const float* b3     = (const float*)d_in[10];
    const float* Wo     = (const float*)d_in[11];
    const float* bo     = (const float*)d_in[12];
    float* out  = (float*)d_out;
    float* embP = (float*)d_ws;   // 50000*30*4 = 6 MB

    // 2048 waves x 25 rows covers 50000+ vocab rows
    embproj_kernel<<<512, 256, 0, stream>>>(emb, Wx, brnn, embP);
    rnn_head_kernel<<<BATCH / 8, 256, 0, stream>>>(
        tokens, embP, Wh, W1, b1, W2, b2, W3, b3, Wo, bo, out);
}